// Round 12
// baseline (170.786 us; speedup 1.0000x reference)
//
#include <hip/hip_runtime.h>

// Problem constants (match reference)
#define BB   8
#define CC   1024
#define TT   4096
#define HH   16
#define KK   31

#define NT   512                // threads per block (8 waves)
#define RPT  8                  // outputs per thread (512 * 8 = 4096 = T)
#define NRD  10                 // ds_read_b128 per thread window (40 floats)
#define PCH  1032               // physical 16B chunks per buffer (8 pads incl.)
#define LPT  2                  // DMA insts per thread per row (1024/512)

typedef float floatx4 __attribute__((ext_vector_type(4)));
typedef const float __attribute__((address_space(1)))* gptr_t;   // global
typedef float __attribute__((address_space(3)))* lptr_t;         // LDS

// Involution swizzle p = q ^ ((q>>3)&7); logical chunk q (holding row floats
// x[4q-16 .. 4q-13]; pads q<4, q>=1028 are zero and are swizzle fixed points)
// lives at physical chunk swz(q). DMA writes physical [4,1028) linearly from
// pre-swizzled source addresses; read pattern q=2*tid+c lands ~2 lanes per
// bank-quad per 16-lane phase (enumerated; near the free wave64 floor).
__device__ __forceinline__ int swz(int q) { return q ^ ((q >> 3) & 7); }

// --- softmax over the 31 taps of each of the 16 heads -> d_ws ---
__global__ void lwconv_softmax_w(const float* __restrict__ w, float* __restrict__ wsm) {
    int h = threadIdx.x;
    if (h < HH) {
        float buf[KK];
        float m = -1e30f;
        #pragma unroll
        for (int k = 0; k < KK; ++k) { buf[k] = w[h * KK + k]; m = fmaxf(m, buf[k]); }
        float s = 0.f;
        #pragma unroll
        for (int k = 0; k < KK; ++k) { buf[k] = expf(buf[k] - m); s += buf[k]; }
        float inv = 1.f / s;
        #pragma unroll
        for (int k = 0; k < KK; ++k) wsm[h * KK + k] = buf[k] * inv;
    }
}

// --- main: block = 8 consecutive channels of one batch (contiguous 128KB);
//     one channel-row per iteration, DMA double-buffer, depth-2 prefetch,
//     counted vmcnt (never 0 mid-loop), raw s_barrier, 8 waves/block ---
// out[t] = bias + sum_k w[k] * x[t + k - 15]
__global__ __launch_bounds__(NT, 8) void lwconv_main(const float* __restrict__ inp,
                                                     const float* __restrict__ wsm,
                                                     const float* __restrict__ bias,
                                                     float* __restrict__ out) {
    __shared__ floatx4 buf[2][PCH];          // 33,024 B -> 4 blocks/CU = 32 waves

    const int blk  = blockIdx.x;             // b*128 + g
    const int b    = blk >> 7;
    const int c0   = (blk & 127) << 3;       // 8 consecutive channels, same head
    const int head = c0 >> 6;
    const int tid  = threadIdx.x;

    const float* base  = inp + ((size_t)b * CC + c0) * TT;
    float*       obase = out + ((size_t)b * CC + c0) * TT;

    // stage channel-row i into buf[i&1]: LDS dest linear over physical [4,1028),
    // source address pre-swizzled (m173 pattern); uniform 2 DMA per thread
    auto stage = [&](int i) {
        const float* rp = base + (size_t)i * TT;
        #pragma unroll
        for (int j = 0; j < LPT; ++j) {
            const int p = 4 + tid + NT * j;      // physical chunk in [4,1028)
            const int q = swz(p);                // logical chunk staged here
            __builtin_amdgcn_global_load_lds((gptr_t)(rp + 4 * (q - 4)),
                                             (lptr_t)(&buf[i & 1][p]), 16, 0, 0);
        }
    };

    // zero the 16 pad chunks (8 per buffer) once
    if (tid < 16) {
        const int pi = tid & 7;
        const int pp = (pi < 4) ? pi : (1024 + pi);    // 0..3, 1028..1031
        buf[tid >> 3][pp] = (floatx4)0.f;
    }

    stage(0);
    stage(1);

    // uniform pre-softmaxed weights + bias (scalar loads, overlap DMA)
    const float* wh = wsm + head * KK;
    float w[KK];
    #pragma unroll
    for (int k = 0; k < KK; ++k) w[k] = wh[k];
    const float bval = bias[head];

    #pragma unroll 1
    for (int r = 0; r < BB; ++r) {
        // Counted wait for row r's 2 DMA (in-order vmcnt retirement).
        // Steady queue: [DMA r | stores r-2 (2), DMA r+1 (2), stores r-1 (2)].
        if (r == 0)
            asm volatile("s_waitcnt vmcnt(2) lgkmcnt(0)" ::: "memory"); // + pad writes
        else if (r == 1 || r == BB - 1)
            asm volatile("s_waitcnt vmcnt(4)" ::: "memory");
        else
            asm volatile("s_waitcnt vmcnt(6)" ::: "memory");
        __builtin_amdgcn_sched_barrier(0);
        __builtin_amdgcn_s_barrier();            // buf[r&1] complete for all waves
        __builtin_amdgcn_sched_barrier(0);

        // window: 10 unconditional ds_read_b128 (pads supply zeros)
        float xv[4 * NRD];
        #pragma unroll
        for (int c = 0; c < NRD; ++c) {
            floatx4 v = buf[r & 1][swz(2 * tid + c)];
            #pragma unroll
            for (int e = 0; e < 4; ++e) xv[4 * c + e] = v[e];
        }
        asm volatile("s_waitcnt lgkmcnt(0)" ::: "memory");   // my reads landed
        __builtin_amdgcn_sched_barrier(0);
        __builtin_amdgcn_s_barrier();            // ALL waves done reading buf[r&1]
        __builtin_amdgcn_sched_barrier(0);

        if (r + 2 < BB) stage(r + 2);            // depth-2 prefetch into freed buffer

        // compute row r entirely in registers, then store
        float acc[RPT];
        #pragma unroll
        for (int p = 0; p < RPT; ++p) acc[p] = bval;
        #pragma unroll
        for (int k = 0; k < KK; ++k) {
            #pragma unroll
            for (int p = 0; p < RPT; ++p)
                acc[p] = fmaf(xv[p + 1 + k], w[k], acc[p]);
        }

        float* orow = obase + (size_t)r * TT + (tid << 3);
        #pragma unroll
        for (int c2 = 0; c2 < RPT / 4; ++c2) {
            floatx4 o = { acc[4 * c2], acc[4 * c2 + 1],
                          acc[4 * c2 + 2], acc[4 * c2 + 3] };
            *reinterpret_cast<floatx4*>(orow + 4 * c2) = o;
        }
    }
}

extern "C" void kernel_launch(void* const* d_in, const int* in_sizes, int n_in,
                              void* d_out, int out_size, void* d_ws, size_t ws_size,
                              hipStream_t stream) {
    const float* inp    = (const float*)d_in[0];   // (B, C, T) fp32
    const float* weight = (const float*)d_in[1];   // (H, 1, K) fp32
    const float* bias   = (const float*)d_in[2];   // (H,) fp32
    float* out = (float*)d_out;
    float* wsm = (float*)d_ws;                     // H*K softmaxed weights

    lwconv_softmax_w<<<1, 64, 0, stream>>>(weight, wsm);

    const int blocks = BB * (CC / 8);              // 1024 blocks = 4/CU
    lwconv_main<<<blocks, NT, 0, stream>>>(inp, wsm, bias, out);
}

// Round 14
// 59.430 us; speedup vs baseline: 2.8737x; 2.8737x over previous
//
#include <hip/hip_runtime.h>

// Problem constants (match reference)
#define BB   8
#define CC   1024
#define TT   4096
#define HH   16
#define KK   31

#define NT    256               // threads per block (4 waves)
#define RPT   8                 // outputs per thread (256 * 8 = 2048 = half row)
#define NRD   10                // ds_read_b128 per thread window (40 floats)
#define MAIN  512               // main 16B chunks (2048 floats of this half)
#define PCH   580               // 512 main + 64 halo + 4 zero
#define HALF  2048              // outputs per block-segment

typedef float floatx4 __attribute__((ext_vector_type(4)));
typedef const float __attribute__((address_space(1)))* gptr_t;   // global
typedef float __attribute__((address_space(3)))* lptr_t;         // LDS

// Involution swizzle on the MAIN region only: p = q ^ ((q>>3)&7), closed and
// bijective on [0,512). Logical main chunk q holds x[h0 + 4q .. +3].
// Halo block: chunks [512,576) hold x[hs + 4m .. +3] (full-wave DMA, all
// waves redundantly -> exec-uniform, per-wave vmcnt stays 3/stage).
// Zero chunks [576,580): never DMA'd, zeroed once.
__device__ __forceinline__ int swz(int q) { return q ^ ((q >> 3) & 7); }

// --- softmax over the 31 taps of each of the 16 heads -> d_ws ---
__global__ void lwconv_softmax_w(const float* __restrict__ w, float* __restrict__ wsm) {
    int h = threadIdx.x;
    if (h < HH) {
        float buf[KK];
        float m = -1e30f;
        #pragma unroll
        for (int k = 0; k < KK; ++k) { buf[k] = w[h * KK + k]; m = fmaxf(m, buf[k]); }
        float s = 0.f;
        #pragma unroll
        for (int k = 0; k < KK; ++k) { buf[k] = expf(buf[k] - m); s += buf[k]; }
        float inv = 1.f / s;
        #pragma unroll
        for (int k = 0; k < KK; ++k) wsm[h * KK + k] = buf[k] * inv;
    }
}

// --- main: block = (batch, 8-channel group, half-row); iterates 8 channels
//     with DMA double-buffer, depth-2 prefetch, counted vmcnt, raw s_barrier ---
// out[t] = bias + sum_k w[k] * x[t + k - 15]
__global__ __launch_bounds__(NT) void lwconv_main(const float* __restrict__ inp,
                                                  const float* __restrict__ wsm,
                                                  const float* __restrict__ bias,
                                                  float* __restrict__ out) {
    __shared__ floatx4 buf[2][PCH];          // 18,560 B -> 8 blocks/CU

    const int blk   = blockIdx.x;            // b*256 + g*2 + half
    const int half  = blk & 1;
    const int g     = (blk >> 1) & 127;
    const int b     = blk >> 8;
    const int c0    = g << 3;                // 8 consecutive channels, same head
    const int head  = c0 >> 6;
    const int tid   = threadIdx.x;

    const int h0 = half * HALF;              // this half's first output t
    const int hs = half ? (HALF - 256) : HALF;         // halo src float base
    const int lowBase = half ? 576 : 580;    // q<0   -> chunk lowBase + q
    const int highAdd = half ? 64 : 0;       // q>=512 -> chunk q + highAdd

    const float* base  = inp + ((size_t)b * CC + c0) * TT;
    float*       obase = out + ((size_t)b * CC + c0) * TT + h0;

    // stage channel i's half-row into buf[i&1]; exactly 3 full-wave DMA/wave
    auto stage = [&](int i) {
        const float* rp = base + (size_t)i * TT;
        #pragma unroll
        for (int j = 0; j < 2; ++j) {
            const int p = tid + NT * j;       // physical main chunk [0,512)
            __builtin_amdgcn_global_load_lds((gptr_t)(rp + h0 + 4 * swz(p)),
                                             (lptr_t)(&buf[i & 1][p]), 16, 0, 0);
        }
        // halo: all 4 waves DMA the same 64 chunks (redundant, benign, uniform)
        const int l = tid & 63;
        __builtin_amdgcn_global_load_lds((gptr_t)(rp + hs + 4 * l),
                                         (lptr_t)(&buf[i & 1][512 + l]), 16, 0, 0);
    };

    // zero the 8 zero-chunks (4 per buffer) once; never touched by DMA
    if (tid < 8) buf[tid >> 2][576 + (tid & 3)] = (floatx4)0.f;

    stage(0);
    stage(1);

    // uniform pre-softmaxed weights + bias (scalar loads, overlap DMA)
    const float* wh = wsm + head * KK;
    float w[KK];
    #pragma unroll
    for (int k = 0; k < KK; ++k) w[k] = wh[k];
    const float bval = bias[head];

    #pragma unroll 1
    for (int r = 0; r < BB; ++r) {
        // Counted wait for row r's 3 DMA (per-wave in-order retirement).
        // Steady: stores r-2 (2) + DMA r+1 (3) + stores r-1 (2) = 7 newer.
        if (r == 0)
            asm volatile("s_waitcnt vmcnt(3) lgkmcnt(0)" ::: "memory");
        else if (r == 1)
            asm volatile("s_waitcnt vmcnt(5)" ::: "memory");
        else if (r == BB - 1)
            asm volatile("s_waitcnt vmcnt(4)" ::: "memory");
        else
            asm volatile("s_waitcnt vmcnt(7)" ::: "memory");
        __builtin_amdgcn_sched_barrier(0);
        __builtin_amdgcn_s_barrier();            // buf[r&1] complete for all waves
        __builtin_amdgcn_sched_barrier(0);

        // window: 10 unconditional ds_read_b128; edge chunks redirect to
        // halo/zero blocks via branchless address selects
        float xv[4 * NRD];
        #pragma unroll
        for (int c = 0; c < NRD; ++c) {
            const int q = 2 * tid + c - 4;       // logical main chunk
            int chunk;
            if (q < 0)           chunk = lowBase + q;
            else if (q >= MAIN)  chunk = q + highAdd;
            else                 chunk = swz(q);
            floatx4 v = buf[r & 1][chunk];
            #pragma unroll
            for (int e = 0; e < 4; ++e) xv[4 * c + e] = v[e];
        }
        asm volatile("s_waitcnt lgkmcnt(0)" ::: "memory");   // my reads landed
        __builtin_amdgcn_sched_barrier(0);
        __builtin_amdgcn_s_barrier();            // ALL waves done reading buf[r&1]
        __builtin_amdgcn_sched_barrier(0);

        if (r + 2 < BB) stage(r + 2);            // depth-2 prefetch into freed buffer

        // compute channel r's half-row, then store
        float acc[RPT];
        #pragma unroll
        for (int p = 0; p < RPT; ++p) acc[p] = bval;
        #pragma unroll
        for (int k = 0; k < KK; ++k) {
            #pragma unroll
            for (int p = 0; p < RPT; ++p)
                acc[p] = fmaf(xv[p + 1 + k], w[k], acc[p]);
        }

        float* orow = obase + (size_t)r * TT + (tid << 3);
        #pragma unroll
        for (int c2 = 0; c2 < RPT / 4; ++c2) {
            floatx4 o = { acc[4 * c2], acc[4 * c2 + 1],
                          acc[4 * c2 + 2], acc[4 * c2 + 3] };
            *reinterpret_cast<floatx4*>(orow + 4 * c2) = o;
        }
    }
}

extern "C" void kernel_launch(void* const* d_in, const int* in_sizes, int n_in,
                              void* d_out, int out_size, void* d_ws, size_t ws_size,
                              hipStream_t stream) {
    const float* inp    = (const float*)d_in[0];   // (B, C, T) fp32
    const float* weight = (const float*)d_in[1];   // (H, 1, K) fp32
    const float* bias   = (const float*)d_in[2];   // (H,) fp32
    float* out = (float*)d_out;
    float* wsm = (float*)d_ws;                     // H*K softmaxed weights

    lwconv_softmax_w<<<1, 64, 0, stream>>>(weight, wsm);

    const int blocks = BB * (CC / 8) * 2;          // 2048 = 8 blocks/CU
    lwconv_main<<<blocks, NT, 0, stream>>>(inp, wsm, bias, out);
}

// Round 15
// 54.678 us; speedup vs baseline: 3.1235x; 1.0869x over previous
//
#include <hip/hip_runtime.h>

// Problem constants (match reference)
#define BB   8
#define CC   1024
#define TT   4096
#define HH   16
#define KK   31

#define NT    256               // threads per block (4 waves)
#define RPT   8                 // outputs per thread (256 * 8 = 2048 = half row)
#define NRD   10               // ds_read_b128 per thread window (40 floats)
#define PCH   520               // 16B chunks per buffer: 4 left + 512 + 4 right
#define HALF  2048              // outputs per block-segment

typedef float floatx4 __attribute__((ext_vector_type(4)));
typedef const float __attribute__((address_space(1)))* gptr_t;   // global
typedef float __attribute__((address_space(3)))* lptr_t;         // LDS

// Involution swizzle p = q ^ ((q>>3)&7): bijective on [0,520) (q<8 and
// q>=512 are fixed points). Logical chunk q holds x[h0 - 16 + 4q .. +3]
// (sources clamped at true row edges; garbage patched in registers).
// Read pattern q = 2*tid + c: per 16-lane phase each bank-quad is hit
// exactly 2x (enumerated) = the free wave64 floor (m136); round 11
// measured exactly this floor with the same pattern.
__device__ __forceinline__ int swz(int q) { return q ^ ((q >> 3) & 7); }

// --- softmax over the 31 taps of each of the 16 heads -> d_ws ---
__global__ void lwconv_softmax_w(const float* __restrict__ w, float* __restrict__ wsm) {
    int h = threadIdx.x;
    if (h < HH) {
        float buf[KK];
        float m = -1e30f;
        #pragma unroll
        for (int k = 0; k < KK; ++k) { buf[k] = w[h * KK + k]; m = fmaxf(m, buf[k]); }
        float s = 0.f;
        #pragma unroll
        for (int k = 0; k < KK; ++k) { buf[k] = expf(buf[k] - m); s += buf[k]; }
        float inv = 1.f / s;
        #pragma unroll
        for (int k = 0; k < KK; ++k) wsm[h * KK + k] = buf[k] * inv;
    }
}

// --- main: block = (batch, 8-channel group, half-row); iterates 8 channels
//     with DMA double-buffer, depth-2 prefetch, counted vmcnt, raw s_barrier ---
// out[t] = bias + sum_k w[k] * x[t + k - 15]
__global__ __launch_bounds__(NT) void lwconv_main(const float* __restrict__ inp,
                                                  const float* __restrict__ wsm,
                                                  const float* __restrict__ bias,
                                                  float* __restrict__ out) {
    __shared__ floatx4 buf[2][PCH];          // 16,640 B -> LDS allows 9 blocks/CU

    const int blk   = blockIdx.x;            // b*256 + g*2 + half
    const int half  = blk & 1;
    const int g     = (blk >> 1) & 127;
    const int b     = blk >> 8;
    const int c0    = g << 3;                // 8 consecutive channels, same head
    const int head  = c0 >> 6;
    const int tid   = threadIdx.x;

    const int h0 = half * HALF;              // this half's first output t

    const float* base  = inp + ((size_t)b * CC + c0) * TT;
    float*       obase = out + ((size_t)b * CC + c0) * TT + h0;

    // stage channel i's half-row into buf[i&1]; exactly 3 exec-uniform DMA/wave
    auto stage = [&](int i) {
        const float* rp = base + (size_t)i * TT;
        // main chunks [4,516): in-bounds sources, no clamp needed
        #pragma unroll
        for (int j = 0; j < 2; ++j) {
            const int p = 4 + tid + NT * j;
            __builtin_amdgcn_global_load_lds((gptr_t)(rp + h0 - 16 + 4 * swz(p)),
                                             (lptr_t)(&buf[i & 1][p]), 16, 0, 0);
        }
        // edge regions [0,64) / [456,520): wave parity picks one (wave-uniform
        // branch -> full exec); 2x redundant coverage, identical bytes; sources
        // clamped at true row edges (garbage patched in registers later)
        const int wv = (tid >> 6) & 1;
        const int l  = tid & 63;
        const int p  = wv ? (456 + l) : l;
        int f = h0 - 16 + 4 * swz(p);
        f = min(max(f, 0), TT - 4);
        __builtin_amdgcn_global_load_lds((gptr_t)(rp + f),
                                         (lptr_t)(&buf[i & 1][p]), 16, 0, 0);
    };

    stage(0);
    stage(1);

    // uniform pre-softmaxed weights + bias (scalar loads, overlap DMA)
    const float* wh = wsm + head * KK;
    float w[KK];
    #pragma unroll
    for (int k = 0; k < KK; ++k) w[k] = wh[k];
    const float bval = bias[head];

    #pragma unroll 1
    for (int r = 0; r < BB; ++r) {
        // Counted wait for row r's 3 DMA (per-wave in-order retirement).
        // Newer ops: r=0 -> DMA_1(3); r=1 -> DMA_2(3)+stores_0(2)=5;
        // steady -> stores(2)+DMA(3)+stores(2)=7; r=7 -> stores+stores=4.
        if (r == 0)
            asm volatile("s_waitcnt vmcnt(3)" ::: "memory");
        else if (r == 1)
            asm volatile("s_waitcnt vmcnt(5)" ::: "memory");
        else if (r == BB - 1)
            asm volatile("s_waitcnt vmcnt(4)" ::: "memory");
        else
            asm volatile("s_waitcnt vmcnt(7)" ::: "memory");
        __builtin_amdgcn_sched_barrier(0);
        __builtin_amdgcn_s_barrier();            // buf[r&1] complete for all waves
        __builtin_amdgcn_sched_barrier(0);

        // window: 10 unconditional ds_read_b128, aligned swizzled pattern
        float xv[4 * NRD];
        #pragma unroll
        for (int c = 0; c < NRD; ++c) {
            floatx4 v = buf[r & 1][swz(2 * tid + c)];
            #pragma unroll
            for (int e = 0; e < 4; ++e) xv[4 * c + e] = v[e];
        }
        asm volatile("s_waitcnt lgkmcnt(0)" ::: "memory");   // my reads landed
        __builtin_amdgcn_sched_barrier(0);
        __builtin_amdgcn_s_barrier();            // ALL waves done reading buf[r&1]
        __builtin_amdgcn_sched_barrier(0);

        if (r + 2 < BB) stage(r + 2);            // depth-2 prefetch into freed buffer

        // register patch of row-edge padding (garbage from clamped DMA).
        // xv[e] = x[h0 + 8*tid - 16 + e]; pad iff global f <0 or >=4096.
        if (half == 0) {
            if (tid < 2) {
                #pragma unroll
                for (int e = 0; e < 16; ++e)
                    xv[e] = (e < 16 - 8 * tid) ? 0.f : xv[e];
            }
        } else {
            if (tid >= NT - 2) {
                #pragma unroll
                for (int e = 24; e < 40; ++e)
                    xv[e] = (e >= 2064 - 8 * tid) ? 0.f : xv[e];
            }
        }

        // compute channel r's half-row, then store
        float acc[RPT];
        #pragma unroll
        for (int p = 0; p < RPT; ++p) acc[p] = bval;
        #pragma unroll
        for (int k = 0; k < KK; ++k) {
            #pragma unroll
            for (int p = 0; p < RPT; ++p)
                acc[p] = fmaf(xv[p + 1 + k], w[k], acc[p]);
        }

        float* orow = obase + (size_t)r * TT + (tid << 3);
        #pragma unroll
        for (int c2 = 0; c2 < RPT / 4; ++c2) {
            floatx4 o = { acc[4 * c2], acc[4 * c2 + 1],
                          acc[4 * c2 + 2], acc[4 * c2 + 3] };
            *reinterpret_cast<floatx4*>(orow + 4 * c2) = o;
        }
    }
}

extern "C" void kernel_launch(void* const* d_in, const int* in_sizes, int n_in,
                              void* d_out, int out_size, void* d_ws, size_t ws_size,
                              hipStream_t stream) {
    const float* inp    = (const float*)d_in[0];   // (B, C, T) fp32
    const float* weight = (const float*)d_in[1];   // (H, 1, K) fp32
    const float* bias   = (const float*)d_in[2];   // (H,) fp32
    float* out = (float*)d_out;
    float* wsm = (float*)d_ws;                     // H*K softmaxed weights

    lwconv_softmax_w<<<1, 64, 0, stream>>>(weight, wsm);

    const int blocks = BB * (CC / 8) * 2;          // 2048 = ~8 blocks/CU
    lwconv_main<<<blocks, NT, 0, stream>>>(inp, wsm, bias, out);
}

// Round 16
// 54.402 us; speedup vs baseline: 3.1393x; 1.0051x over previous
//
#include <hip/hip_runtime.h>

// Problem constants (match reference)
#define BB   8
#define CC   1024
#define TT   4096
#define HH   16
#define KK   31

#define NT    256               // threads per block (4 independent waves)
#define RPT   8                 // outputs per thread
#define NRD   10                // ds_read_b128 per thread window (40 floats)
#define WCH   136               // 16B chunks per wave buffer: 4 halo + 128 + 4 halo
#define SEGW  512               // outputs per wave-segment
#define HALF  2048              // outputs per block (4 waves * 512)

typedef float floatx4 __attribute__((ext_vector_type(4)));
typedef const float __attribute__((address_space(1)))* gptr_t;   // global
typedef float __attribute__((address_space(3)))* lptr_t;         // LDS

// Involution swizzle p = q ^ ((q>>3)&7): bijective on [0,136) (q>=128 fixed).
// Wave-logical chunk q holds x[seg0 - 16 + 4q .. +3] (sources clamped at true
// row edges; garbage patched in registers). Read pattern q = 2*l + c: per
// 16-lane phase each bank-quad is hit 2x (enumerated) ~ the wave64 floor.
__device__ __forceinline__ int swz(int q) { return q ^ ((q >> 3) & 7); }

// --- softmax over the 31 taps of each of the 16 heads -> d_ws ---
__global__ void lwconv_softmax_w(const float* __restrict__ w, float* __restrict__ wsm) {
    int h = threadIdx.x;
    if (h < HH) {
        float buf[KK];
        float m = -1e30f;
        #pragma unroll
        for (int k = 0; k < KK; ++k) { buf[k] = w[h * KK + k]; m = fmaxf(m, buf[k]); }
        float s = 0.f;
        #pragma unroll
        for (int k = 0; k < KK; ++k) { buf[k] = expf(buf[k] - m); s += buf[k]; }
        float inv = 1.f / s;
        #pragma unroll
        for (int k = 0; k < KK; ++k) wsm[h * KK + k] = buf[k] * inv;
    }
}

// --- main: block = (batch, 8-channel group, half-row); each of the 4 waves
//     owns a 512-output sub-segment with a PRIVATE double buffer. Iterates 8
//     channels with DMA double-buffer, depth-2 prefetch, counted vmcnt.
//     ZERO barriers: waves free-run, self-staggering their DMA bursts. ---
// out[t] = bias + sum_k w[k] * x[t + k - 15]
__global__ __launch_bounds__(NT) void lwconv_main(const float* __restrict__ inp,
                                                  const float* __restrict__ wsm,
                                                  const float* __restrict__ bias,
                                                  float* __restrict__ out) {
    __shared__ floatx4 buf[4][2][WCH];       // 17,408 B -> 8 blocks/CU (wave cap)

    const int blk   = blockIdx.x;            // b*256 + g*2 + half
    const int half  = blk & 1;
    const int g     = (blk >> 1) & 127;
    const int b     = blk >> 8;
    const int c0    = g << 3;                // 8 consecutive channels, same head
    const int head  = c0 >> 6;
    const int tid   = threadIdx.x;
    const int wv    = tid >> 6;              // wave 0..3
    const int l     = tid & 63;              // lane

    const int seg0 = half * HALF + wv * SEGW;      // this wave's first output t

    const float* base  = inp + ((size_t)b * CC + c0) * TT;
    float*       obase = out + ((size_t)b * CC + c0) * TT;

    // stage channel i's wave-segment into buf[wv][i&1]: exactly 3 exec-uniform
    // DMA; insts cover chunks [0,64)+[64,128)+[72,136) (overlap = same bytes,
    // benign; redundant fetch L2-absorbed). Sources clamped at row edges.
    auto stage = [&](int i) {
        const float* rp = base + (size_t)i * TT;
        floatx4* wbuf = &buf[wv][i & 1][0];
        #pragma unroll
        for (int j = 0; j < 3; ++j) {
            const int p = (j == 2) ? (72 + l) : (j * 64 + l);   // physical chunk
            int f = seg0 - 16 + 4 * swz(p);                     // logical source
            f = min(max(f, 0), TT - 4);
            __builtin_amdgcn_global_load_lds((gptr_t)(rp + f),
                                             (lptr_t)(&wbuf[p]), 16, 0, 0);
        }
    };

    stage(0);
    stage(1);

    // uniform pre-softmaxed weights + bias (scalar loads, overlap DMA)
    const float* wh = wsm + head * KK;
    float w[KK];
    #pragma unroll
    for (int k = 0; k < KK; ++k) w[k] = wh[k];
    const float bval = bias[head];

    #pragma unroll 1
    for (int r = 0; r < BB; ++r) {
        // Counted wait for row r's 3 DMA (per-wave in-order retirement).
        // Newer ops: r=0 -> DMA_1(3); r=1 -> DMA_2(3)+stores_0(2)=5;
        // steady -> stores(2)+DMA(3)+stores(2)=7; r=7 -> stores+stores=4.
        if (r == 0)
            asm volatile("s_waitcnt vmcnt(3)" ::: "memory");
        else if (r == 1)
            asm volatile("s_waitcnt vmcnt(5)" ::: "memory");
        else if (r == BB - 1)
            asm volatile("s_waitcnt vmcnt(4)" ::: "memory");
        else
            asm volatile("s_waitcnt vmcnt(7)" ::: "memory");
        __builtin_amdgcn_sched_barrier(0);

        // window: 10 unconditional ds_read_b128 from this wave's buffer
        float xv[4 * NRD];
        #pragma unroll
        for (int c = 0; c < NRD; ++c) {
            floatx4 v = buf[wv][r & 1][swz(2 * l + c)];
            #pragma unroll
            for (int e = 0; e < 4; ++e) xv[4 * c + e] = v[e];
        }
        asm volatile("s_waitcnt lgkmcnt(0)" ::: "memory");   // reads in regs
        __builtin_amdgcn_sched_barrier(0);

        if (r + 2 < BB) stage(r + 2);        // refill MY buffer (wave-local safe)
        __builtin_amdgcn_sched_barrier(0);

        // register patch of row-edge padding (garbage from clamped DMA).
        // xv[e] = x[seg0 + 8*l - 16 + e]; zero iff global index <0 or >=4096.
        if (half == 0) {
            if (tid < 2) {
                #pragma unroll
                for (int e = 0; e < 16; ++e)
                    xv[e] = (e < 16 - 8 * tid) ? 0.f : xv[e];
            }
        } else {
            if (tid >= NT - 2) {
                #pragma unroll
                for (int e = 24; e < 40; ++e)
                    xv[e] = (e >= 2064 - 8 * tid) ? 0.f : xv[e];
            }
        }

        // compute channel r's 8 outputs, then store
        float acc[RPT];
        #pragma unroll
        for (int p = 0; p < RPT; ++p) acc[p] = bval;
        #pragma unroll
        for (int k = 0; k < KK; ++k) {
            #pragma unroll
            for (int p = 0; p < RPT; ++p)
                acc[p] = fmaf(xv[p + 1 + k], w[k], acc[p]);
        }

        float* orow = obase + (size_t)r * TT + seg0 + (l << 3);
        #pragma unroll
        for (int c2 = 0; c2 < RPT / 4; ++c2) {
            floatx4 o = { acc[4 * c2], acc[4 * c2 + 1],
                          acc[4 * c2 + 2], acc[4 * c2 + 3] };
            *reinterpret_cast<floatx4*>(orow + 4 * c2) = o;
        }
    }
}

extern "C" void kernel_launch(void* const* d_in, const int* in_sizes, int n_in,
                              void* d_out, int out_size, void* d_ws, size_t ws_size,
                              hipStream_t stream) {
    const float* inp    = (const float*)d_in[0];   // (B, C, T) fp32
    const float* weight = (const float*)d_in[1];   // (H, 1, K) fp32
    const float* bias   = (const float*)d_in[2];   // (H,) fp32
    float* out = (float*)d_out;
    float* wsm = (float*)d_ws;                     // H*K softmaxed weights

    lwconv_softmax_w<<<1, 64, 0, stream>>>(weight, wsm);

    const int blocks = BB * (CC / 8) * 2;          // 2048 = 8 blocks/CU exactly
    lwconv_main<<<blocks, NT, 0, stream>>>(inp, wsm, bias, out);
}